// Round 1
// baseline (181.000 us; speedup 1.0000x reference)
//
#include <hip/hip_runtime.h>
#include <hip/hip_bf16.h>
#include <cstdint>
#include <cstddef>

// Problem constants
#define B_ 64
#define S_ 4096
#define D_ 256
#define BM 128                  // rows per block
#define BK 64                   // k-chunk
#define LDA_PAD 72              // LDS row stride in shorts (64 + 8 pad)
#define NBLK (B_ * S_ / BM)     // 2048
#define BLKS_PER_B (S_ / BM)    // 32

typedef __attribute__((ext_vector_type(8))) short short8;
typedef __attribute__((ext_vector_type(4))) short short4v;
typedef __attribute__((ext_vector_type(4))) float f32x4;
typedef __attribute__((ext_vector_type(4))) float f4;

__device__ __forceinline__ short f2bf(float f) {
  union { float f; uint32_t u; } v; v.f = f;
  uint32_t r = v.u + 0x7FFFu + ((v.u >> 16) & 1u);   // RNE
  return (short)(r >> 16);
}

__device__ __forceinline__ float fast_tanh(float z) {
  // tanh(z) = 1 - 2/(e^{2z}+1); overflow-safe (exp->inf => 1, exp->0 => -1)
  return 1.0f - 2.0f / (__expf(2.0f * z) + 1.0f);
}

// Kernel 0: Wt[n][k] = bf16(W[k][n]) via LDS tile transpose. grid 16, 256 thr.
__global__ void k_pack(const float* __restrict__ W, short* __restrict__ wt) {
  __shared__ float tile[64][65];
  int t = blockIdx.x, ti = t >> 2, tj = t & 3;
  int tid = threadIdx.x;
#pragma unroll
  for (int i = 0; i < 16; ++i) {
    int idx = i * 256 + tid;
    int r = idx >> 6, c = idx & 63;                 // r: k-local, c: n-local
    tile[c][r] = W[(ti * 64 + r) * 256 + tj * 64 + c];
  }
  __syncthreads();
#pragma unroll
  for (int i = 0; i < 16; ++i) {
    int idx = i * 256 + tid;
    int r = idx >> 6, c = idx & 63;                 // r: n-local, c: k-local
    wt[(tj * 64 + r) * 256 + ti * 64 + c] = f2bf(tile[r][c]);
  }
}

// Kernel 1: fused GEMM(x@W)+tanh+dot(u) -> scores; per-block softmax partials
// (m, l) and context partial sum_s e_s * x[s,:]. grid NBLK, 256 thr (4 waves).
__global__ __launch_bounds__(256, 2)
void k_scores(const float* __restrict__ x, const short* __restrict__ wt,
              const float* __restrict__ bias, const float* __restrict__ u,
              float* __restrict__ ws_scores, float* __restrict__ ws_m,
              float* __restrict__ ws_l, float* __restrict__ ws_c) {
  __shared__ short lsA[BM * LDA_PAD];      // 18432 B
  __shared__ short lsB[D_ * LDA_PAD];      // 36864 B
  __shared__ float score_lds[BM];
  __shared__ float e_lds[BM];
  __shared__ float red_lds[2];

  const int tid = threadIdx.x;
  const int bid = blockIdx.x;
  const int m0 = bid * BM;
  const int lane = tid & 63;
  const int wv = tid >> 6;
  const int cl = lane & 15;
  const int gr = lane >> 4;
  const int wrow = wv * 32;

  f32x4 acc[2][16];
#pragma unroll
  for (int i = 0; i < 2; ++i)
#pragma unroll
    for (int j = 0; j < 16; ++j)
      acc[i][j] = (f32x4){0.f, 0.f, 0.f, 0.f};

  for (int kc = 0; kc < 4; ++kc) {
    __syncthreads();
    // stage A: 128 rows x 64 k of x (fp32 -> bf16)
#pragma unroll
    for (int i = 0; i < 8; ++i) {
      int idx = tid + i * 256;
      int r = idx >> 4, c4 = idx & 15;
      f4 v = *(const f4*)(x + (size_t)(m0 + r) * D_ + kc * BK + c4 * 4);
      short4v s;
      s[0] = f2bf(v[0]); s[1] = f2bf(v[1]); s[2] = f2bf(v[2]); s[3] = f2bf(v[3]);
      *(short4v*)&lsA[r * LDA_PAD + c4 * 4] = s;
    }
    // stage B: Wt chunk, 256 rows x 64 k (already bf16)
#pragma unroll
    for (int i = 0; i < 8; ++i) {
      int idx = tid + i * 256;
      int n = idx >> 3, c8 = idx & 7;
      short8 w = *(const short8*)(wt + n * D_ + kc * BK + c8 * 8);
      *(short8*)&lsB[n * LDA_PAD + c8 * 8] = w;
    }
    __syncthreads();
#pragma unroll
    for (int ks = 0; ks < 2; ++ks) {
      short8 a0 = *(const short8*)&lsA[(wrow + cl) * LDA_PAD + ks * 32 + gr * 8];
      short8 a1 = *(const short8*)&lsA[(wrow + 16 + cl) * LDA_PAD + ks * 32 + gr * 8];
#pragma unroll
      for (int nf = 0; nf < 16; ++nf) {
        short8 bfr = *(const short8*)&lsB[(nf * 16 + cl) * LDA_PAD + ks * 32 + gr * 8];
        acc[0][nf] = __builtin_amdgcn_mfma_f32_16x16x32_bf16(a0, bfr, acc[0][nf], 0, 0, 0);
        acc[1][nf] = __builtin_amdgcn_mfma_f32_16x16x32_bf16(a1, bfr, acc[1][nf], 0, 0, 0);
      }
    }
  }

  // Epilogue: score[row] = sum_n tanh(acc[row][n] + b[n]) * u[n]
  float bv[16], uv[16];
#pragma unroll
  for (int nf = 0; nf < 16; ++nf) {
    bv[nf] = bias[nf * 16 + cl];
    uv[nf] = u[nf * 16 + cl];
  }
#pragma unroll
  for (int mi = 0; mi < 2; ++mi) {
    float p0 = 0.f, p1 = 0.f, p2 = 0.f, p3 = 0.f;
#pragma unroll
    for (int nf = 0; nf < 16; ++nf) {
      p0 += fast_tanh(acc[mi][nf][0] + bv[nf]) * uv[nf];
      p1 += fast_tanh(acc[mi][nf][1] + bv[nf]) * uv[nf];
      p2 += fast_tanh(acc[mi][nf][2] + bv[nf]) * uv[nf];
      p3 += fast_tanh(acc[mi][nf][3] + bv[nf]) * uv[nf];
    }
#pragma unroll
    for (int m = 1; m < 16; m <<= 1) {
      p0 += __shfl_xor(p0, m);
      p1 += __shfl_xor(p1, m);
      p2 += __shfl_xor(p2, m);
      p3 += __shfl_xor(p3, m);
    }
    if (cl == 0) {
      int r = wrow + mi * 16 + gr * 4;
      score_lds[r + 0] = p0;
      score_lds[r + 1] = p1;
      score_lds[r + 2] = p2;
      score_lds[r + 3] = p3;
      ws_scores[m0 + r + 0] = p0;
      ws_scores[m0 + r + 1] = p1;
      ws_scores[m0 + r + 2] = p2;
      ws_scores[m0 + r + 3] = p3;
    }
  }
  __syncthreads();
  // block max over the 128 scores
  if (tid < 64) {
    float v = fmaxf(score_lds[tid], score_lds[tid + 64]);
#pragma unroll
    for (int m = 32; m >= 1; m >>= 1) v = fmaxf(v, __shfl_xor(v, m));
    if (tid == 0) red_lds[0] = v;
  }
  __syncthreads();
  float mb = red_lds[0];
  if (tid < BM) e_lds[tid] = __expf(score_lds[tid] - mb);
  __syncthreads();
  if (tid < 64) {
    float v = e_lds[tid] + e_lds[tid + 64];
#pragma unroll
    for (int m = 32; m >= 1; m >>= 1) v += __shfl_xor(v, m);
    if (tid == 0) { ws_m[bid] = mb; ws_l[bid] = v; }
  }
  // context partial: thread owns column d = tid; x tile is L2-hot
  float cacc = 0.f;
  const float* xp = x + (size_t)m0 * D_ + tid;
#pragma unroll 4
  for (int s = 0; s < BM; ++s) cacc += e_lds[s] * xp[(size_t)s * D_];
  ws_c[bid * D_ + tid] = cacc;
}

// Kernel 2: per-batch combine of 32 block partials -> context out + (M, L)
__global__ void k_combine(const float* __restrict__ ws_m, const float* __restrict__ ws_l,
                          const float* __restrict__ ws_c, float* __restrict__ out_ctx,
                          float* __restrict__ ws_M, float* __restrict__ ws_L) {
  int b = blockIdx.x, d = threadIdx.x;
  float M = -1e30f;
#pragma unroll
  for (int i = 0; i < BLKS_PER_B; ++i) M = fmaxf(M, ws_m[b * BLKS_PER_B + i]);
  float L = 0.f, c = 0.f;
#pragma unroll
  for (int i = 0; i < BLKS_PER_B; ++i) {
    float f = __expf(ws_m[b * BLKS_PER_B + i] - M);
    L += ws_l[b * BLKS_PER_B + i] * f;
    c += ws_c[(b * BLKS_PER_B + i) * D_ + d] * f;
  }
  out_ctx[b * D_ + d] = c / L;
  if (d == 0) { ws_M[b] = M; ws_L[b] = L; }
}

// Kernel 3: weights[b,s] = exp(score - M_b) / L_b
__global__ void k_weights(const float* __restrict__ ws_scores, const float* __restrict__ ws_M,
                          const float* __restrict__ ws_L, float* __restrict__ out_w) {
  int idx = blockIdx.x * 256 + threadIdx.x;
  int b = idx >> 12;
  out_w[idx] = __expf(ws_scores[idx] - ws_M[b]) / ws_L[b];
}

extern "C" void kernel_launch(void* const* d_in, const int* in_sizes, int n_in,
                              void* d_out, int out_size, void* d_ws, size_t ws_size,
                              hipStream_t stream) {
  (void)in_sizes; (void)n_in; (void)out_size; (void)ws_size;
  const float* x    = (const float*)d_in[0];
  const float* W    = (const float*)d_in[1];
  const float* bias = (const float*)d_in[2];
  const float* u    = (const float*)d_in[3];
  float* out_ctx = (float*)d_out;                 // [64,256]
  float* out_w   = (float*)d_out + B_ * D_;       // [64,4096]

  char* ws = (char*)d_ws;
  short* wt        = (short*)(ws + 0);            // 131072 B
  float* ws_scores = (float*)(ws + 131072);       // 1048576 B
  float* ws_m      = (float*)(ws + 1179648);      // 8192 B
  float* ws_l      = (float*)(ws + 1187840);      // 8192 B
  float* ws_c      = (float*)(ws + 1196032);      // 2097152 B
  float* ws_M      = (float*)(ws + 3293184);      // 256 B
  float* ws_L      = (float*)(ws + 3293440);      // 256 B

  hipLaunchKernelGGL(k_pack, dim3(16), dim3(256), 0, stream, W, wt);
  hipLaunchKernelGGL(k_scores, dim3(NBLK), dim3(256), 0, stream,
                     x, wt, bias, u, ws_scores, ws_m, ws_l, ws_c);
  hipLaunchKernelGGL(k_combine, dim3(B_), dim3(256), 0, stream,
                     ws_m, ws_l, ws_c, out_ctx, ws_M, ws_L);
  hipLaunchKernelGGL(k_weights, dim3(B_ * S_ / 256), dim3(256), 0, stream,
                     ws_scores, ws_M, ws_L, out_w);
}

// Round 2
// 117.817 us; speedup vs baseline: 1.5363x; 1.5363x over previous
//
#include <hip/hip_runtime.h>
#include <hip/hip_bf16.h>
#include <cstdint>
#include <cstddef>

// Problem constants
#define B_ 64
#define S_ 4096
#define D_ 256
#define BM 64                   // rows per block (4 waves x 16 rows)
#define BK 64                   // k-chunk
#define NBLK (B_ * S_ / BM)     // 4096
#define BLKS_PER_B (S_ / BM)    // 64

typedef __attribute__((ext_vector_type(8))) short short8;
typedef __attribute__((ext_vector_type(4))) float f32x4;
typedef __attribute__((ext_vector_type(4))) float f4;

__device__ __forceinline__ short f2bf(float f) {
  union { float f; uint32_t u; } v; v.f = f;
  uint32_t r = v.u + 0x7FFFu + ((v.u >> 16) & 1u);   // RNE
  return (short)(r >> 16);
}

__device__ __forceinline__ float fast_tanh(float z) {
  // tanh(z) = 1 - 2/(e^{2z}+1); overflow-safe
  return 1.0f - 2.0f / (__expf(2.0f * z) + 1.0f);
}

__device__ __forceinline__ void gload_lds16(const short* g, short* l) {
  __builtin_amdgcn_global_load_lds(
      (const __attribute__((address_space(1))) int*)(g),
      (__attribute__((address_space(3))) int*)(l), 16, 0, 0);
}

// Kernel 0: Wt[n][k] = bf16(W[k][n]) via LDS tile transpose. grid 16, 256 thr.
__global__ void k_pack(const float* __restrict__ W, short* __restrict__ wt) {
  __shared__ float tile[64][65];
  int t = blockIdx.x, ti = t >> 2, tj = t & 3;
  int tid = threadIdx.x;
#pragma unroll
  for (int i = 0; i < 16; ++i) {
    int idx = i * 256 + tid;
    int r = idx >> 6, c = idx & 63;                 // r: k-local, c: n-local
    tile[c][r] = W[(ti * 64 + r) * 256 + tj * 64 + c];
  }
  __syncthreads();
#pragma unroll
  for (int i = 0; i < 16; ++i) {
    int idx = i * 256 + tid;
    int r = idx >> 6, c = idx & 63;                 // r: n-local, c: k-local
    wt[(tj * 64 + r) * 256 + ti * 64 + c] = f2bf(tile[r][c]);
  }
}

// Kernel 1: fused GEMM(x@W)+tanh+dot(u) -> scores; per-block softmax partials
// (m, l) and context partial sum_s e_s * x[s,:]. grid NBLK, 256 thr (4 waves,
// 16 rows each). A direct global->reg; B async-staged in LDS (swizzled).
__global__ __launch_bounds__(256, 3)
void k_scores(const float* __restrict__ x, const short* __restrict__ wt,
              const float* __restrict__ bias, const float* __restrict__ u,
              float* __restrict__ ws_scores, float* __restrict__ ws_m,
              float* __restrict__ ws_l, float* __restrict__ ws_c) {
  __shared__ __align__(16) short lsB[D_ * BK];   // [256 n][64 k] shorts, 32 KB, swizzled
  __shared__ float score_lds[BM];
  __shared__ float e_lds[BM];
  __shared__ float red_lds[1];

  const int tid = threadIdx.x;
  const int bid = blockIdx.x;
  const int m0 = bid * BM;
  const int lane = tid & 63;
  const int wv = tid >> 6;         // 0..3 : 16-row group
  const int cl = lane & 15;
  const int gr = lane >> 4;        // 0..3

  // B stage: issue i covers idx=i*256+tid -> n=idx>>3, c8=idx&7.
  // LDS linear dest byte = idx*16 ; global source column pre-swizzled c8^(n&7).
  const int st_n  = ((0 * 256 + tid) >> 3);  // recomputed per issue below
  (void)st_n;

  f32x4 acc[16];
#pragma unroll
  for (int j = 0; j < 16; ++j) acc[j] = (f32x4){0.f, 0.f, 0.f, 0.f};

  // stage kc=0
#pragma unroll
  for (int i = 0; i < 8; ++i) {
    int idx = i * 256 + tid;
    int n = idx >> 3, c8 = idx & 7;
    gload_lds16(wt + n * 256 + ((c8 ^ (n & 7)) << 3), &lsB[idx * 8]);
  }

  const float* xrow = x + (size_t)(m0 + wv * 16 + cl) * D_;
  const int roff = cl * 64;                       // r*64 - nf*1024 added in loop
  const int sw0 = ((0 + gr) ^ (cl & 7)) << 3;     // ks=0 quad swizzle (shorts)
  const int sw1 = ((4 + gr) ^ (cl & 7)) << 3;     // ks=1

  for (int kc = 0; kc < 4; ++kc) {
    // A fragments direct from global (fp32)
    f4 a00 = *(const f4*)(xrow + kc * 64 + gr * 8);
    f4 a01 = *(const f4*)(xrow + kc * 64 + gr * 8 + 4);
    f4 a10 = *(const f4*)(xrow + kc * 64 + 32 + gr * 8);
    f4 a11 = *(const f4*)(xrow + kc * 64 + 32 + gr * 8 + 4);
    __syncthreads();   // B(kc) staged (vmcnt drain also covers A loads)

    short8 af0, af1;
    af0[0] = f2bf(a00[0]); af0[1] = f2bf(a00[1]); af0[2] = f2bf(a00[2]); af0[3] = f2bf(a00[3]);
    af0[4] = f2bf(a01[0]); af0[5] = f2bf(a01[1]); af0[6] = f2bf(a01[2]); af0[7] = f2bf(a01[3]);
    af1[0] = f2bf(a10[0]); af1[1] = f2bf(a10[1]); af1[2] = f2bf(a10[2]); af1[3] = f2bf(a10[3]);
    af1[4] = f2bf(a11[0]); af1[5] = f2bf(a11[1]); af1[6] = f2bf(a11[2]); af1[7] = f2bf(a11[3]);

#pragma unroll
    for (int nf = 0; nf < 16; ++nf) {
      short8 b0 = *(const short8*)&lsB[nf * 1024 + roff + sw0];
      acc[nf] = __builtin_amdgcn_mfma_f32_16x16x32_bf16(af0, b0, acc[nf], 0, 0, 0);
      short8 b1 = *(const short8*)&lsB[nf * 1024 + roff + sw1];
      acc[nf] = __builtin_amdgcn_mfma_f32_16x16x32_bf16(af1, b1, acc[nf], 0, 0, 0);
    }
    __syncthreads();   // all waves done reading lsB
    if (kc < 3) {
#pragma unroll
      for (int i = 0; i < 8; ++i) {
        int idx = i * 256 + tid;
        int n = idx >> 3, c8 = idx & 7;
        gload_lds16(wt + n * 256 + (kc + 1) * 64 + ((c8 ^ (n & 7)) << 3), &lsB[idx * 8]);
      }
    }
  }

  // Epilogue: score[row] = sum_n tanh(acc[row][n] + b[n]) * u[n]
  float bv[16], uv[16];
#pragma unroll
  for (int nf = 0; nf < 16; ++nf) {
    bv[nf] = bias[nf * 16 + cl];
    uv[nf] = u[nf * 16 + cl];
  }
  float p0 = 0.f, p1 = 0.f, p2 = 0.f, p3 = 0.f;
#pragma unroll
  for (int nf = 0; nf < 16; ++nf) {
    p0 += fast_tanh(acc[nf][0] + bv[nf]) * uv[nf];
    p1 += fast_tanh(acc[nf][1] + bv[nf]) * uv[nf];
    p2 += fast_tanh(acc[nf][2] + bv[nf]) * uv[nf];
    p3 += fast_tanh(acc[nf][3] + bv[nf]) * uv[nf];
  }
#pragma unroll
  for (int m = 1; m < 16; m <<= 1) {
    p0 += __shfl_xor(p0, m);
    p1 += __shfl_xor(p1, m);
    p2 += __shfl_xor(p2, m);
    p3 += __shfl_xor(p3, m);
  }
  if (cl == 0) {
    int r = wv * 16 + gr * 4;
    score_lds[r + 0] = p0;
    score_lds[r + 1] = p1;
    score_lds[r + 2] = p2;
    score_lds[r + 3] = p3;
    ws_scores[m0 + r + 0] = p0;
    ws_scores[m0 + r + 1] = p1;
    ws_scores[m0 + r + 2] = p2;
    ws_scores[m0 + r + 3] = p3;
  }
  __syncthreads();
  // block max over 64 scores (wave 0)
  if (tid < 64) {
    float v = score_lds[tid];
#pragma unroll
    for (int m = 32; m >= 1; m >>= 1) v = fmaxf(v, __shfl_xor(v, m));
    if (tid == 0) red_lds[0] = v;
  }
  __syncthreads();
  float mb = red_lds[0];
  if (tid < BM) e_lds[tid] = __expf(score_lds[tid] - mb);
  __syncthreads();
  if (tid < 64) {
    float v = e_lds[tid];
#pragma unroll
    for (int m = 32; m >= 1; m >>= 1) v += __shfl_xor(v, m);
    if (tid == 0) { ws_m[bid] = mb; ws_l[bid] = v; }
  }
  // context partial: thread owns column d = tid; x tile is L1/L2-hot
  float cacc = 0.f;
  const float* xp = x + (size_t)m0 * D_ + tid;
#pragma unroll 4
  for (int s = 0; s < BM; ++s) cacc += e_lds[s] * xp[(size_t)s * D_];
  ws_c[bid * D_ + tid] = cacc;
}

// Kernel 2: per-batch combine of 64 block partials -> context out + (M, L)
__global__ void k_combine(const float* __restrict__ ws_m, const float* __restrict__ ws_l,
                          const float* __restrict__ ws_c, float* __restrict__ out_ctx,
                          float* __restrict__ ws_M, float* __restrict__ ws_L) {
  int b = blockIdx.x, d = threadIdx.x;
  float M = -1e30f;
#pragma unroll
  for (int i = 0; i < BLKS_PER_B; ++i) M = fmaxf(M, ws_m[b * BLKS_PER_B + i]);
  float L = 0.f, c = 0.f;
#pragma unroll 4
  for (int i = 0; i < BLKS_PER_B; ++i) {
    float f = __expf(ws_m[b * BLKS_PER_B + i] - M);
    L += ws_l[b * BLKS_PER_B + i] * f;
    c += ws_c[(b * BLKS_PER_B + i) * D_ + d] * f;
  }
  out_ctx[b * D_ + d] = c / L;
  if (d == 0) { ws_M[b] = M; ws_L[b] = L; }
}

// Kernel 3: weights[b,s] = exp(score - M_b) / L_b
__global__ void k_weights(const float* __restrict__ ws_scores, const float* __restrict__ ws_M,
                          const float* __restrict__ ws_L, float* __restrict__ out_w) {
  int idx = blockIdx.x * 256 + threadIdx.x;
  int b = idx >> 12;
  out_w[idx] = __expf(ws_scores[idx] - ws_M[b]) / ws_L[b];
}

extern "C" void kernel_launch(void* const* d_in, const int* in_sizes, int n_in,
                              void* d_out, int out_size, void* d_ws, size_t ws_size,
                              hipStream_t stream) {
  (void)in_sizes; (void)n_in; (void)out_size; (void)ws_size;
  const float* x    = (const float*)d_in[0];
  const float* W    = (const float*)d_in[1];
  const float* bias = (const float*)d_in[2];
  const float* u    = (const float*)d_in[3];
  float* out_ctx = (float*)d_out;                 // [64,256]
  float* out_w   = (float*)d_out + B_ * D_;       // [64,4096]

  char* ws = (char*)d_ws;
  short* wt        = (short*)(ws + 0);            // 131072 B
  float* ws_scores = (float*)(ws + 131072);       // 1048576 B
  float* ws_m      = (float*)(ws + 1179648);      // 16384 B
  float* ws_l      = (float*)(ws + 1196032);      // 16384 B
  float* ws_c      = (float*)(ws + 1212416);      // 4194304 B
  float* ws_M      = (float*)(ws + 5406720);      // 256 B
  float* ws_L      = (float*)(ws + 5406976);      // 256 B

  hipLaunchKernelGGL(k_pack, dim3(16), dim3(256), 0, stream, W, wt);
  hipLaunchKernelGGL(k_scores, dim3(NBLK), dim3(256), 0, stream,
                     x, wt, bias, u, ws_scores, ws_m, ws_l, ws_c);
  hipLaunchKernelGGL(k_combine, dim3(B_), dim3(256), 0, stream,
                     ws_m, ws_l, ws_c, out_ctx, ws_M, ws_L);
  hipLaunchKernelGGL(k_weights, dim3(B_ * S_ / 256), dim3(256), 0, stream,
                     ws_scores, ws_M, ws_L, out_w);
}